// Round 2
// baseline (222.006 us; speedup 1.0000x reference)
//
#include <hip/hip_runtime.h>

namespace {
constexpr int IW = 512;
constexpr int IH = 512;
constexpr int ID = 64;
constexpr int IN = 2;           // batch (C=1)
constexpr float W_Z  = 0.5f;                     // CONTIZ^2
constexpr float W_XY = 2.0f;
constexpr float W_XZ = 1.41421356237309515f;     // 2*CONTIZ = sqrt(2)

constexpr int CHUNKS = IN * ID * IH * (IW / 4);  // 8,388,608 float4 chunks
constexpr int TPB    = 256;
constexpr int BLOCKS = 2048;
constexpr int ITERS  = CHUNKS / (BLOCKS * TPB);  // 16, exact
}

__global__ __launch_bounds__(TPB) void HessianReg_kernel(const float* __restrict__ img,
                                                         float* __restrict__ out) {
    const int tid0 = blockIdx.x * TPB + threadIdx.x;
    float acc = 0.f;

    for (int it = 0; it < ITERS; ++it) {
        const int cid   = tid0 + it * (BLOCKS * TPB);
        const int chunk = cid & 127;            // float4 index within row
        const int row   = cid >> 7;             // (n*ID + d)*IH + h
        const int h     = row & (IH - 1);
        const int d     = (row >> 9) & (ID - 1);
        const int w0    = chunk << 2;

        const float* p = img + (size_t)row * IW + w0;

        const bool hasW = (w0 < IW - 4);        // w0 <= 504: a4/a5 in-row
        const bool hy2  = (h < IH - 1);
        const bool hy3  = (h < IH - 2);
        const bool dz2  = (d < ID - 1);
        const bool dz3  = (d < ID - 2);

        const float4 a = *(const float4*)p;     // row (d,h), w0..w0+3
        float a4 = 0.f, a5 = 0.f;
        if (hasW) { a4 = p[4]; a5 = p[5]; }

        float4 b = make_float4(0.f, 0.f, 0.f, 0.f);  // (d,   h+1)
        float4 c = make_float4(0.f, 0.f, 0.f, 0.f);  // (d,   h+2)
        float4 e = make_float4(0.f, 0.f, 0.f, 0.f);  // (d+1, h  )
        float4 f = make_float4(0.f, 0.f, 0.f, 0.f);  // (d+2, h  )
        float4 g = make_float4(0.f, 0.f, 0.f, 0.f);  // (d+1, h+1)
        float b4 = 0.f, e4 = 0.f;

        if (hy2) { b = *(const float4*)(p + IW); if (hasW) b4 = p[IW + 4]; }
        if (hy3) { c = *(const float4*)(p + 2 * IW); }
        if (dz2) { e = *(const float4*)(p + (size_t)IH * IW); if (hasW) e4 = p[(size_t)IH * IW + 4]; }
        if (dz3) { f = *(const float4*)(p + (size_t)2 * IH * IW); }
        if (dz2 && hy2) { g = *(const float4*)(p + (size_t)IH * IW + IW); }

        // g_xx: anchors w0..w0+3, needs x[w..w+2] in-row
        {
            float s = fabsf(a.x - 2.f * a.y + a.z) + fabsf(a.y - 2.f * a.z + a.w);
            if (hasW) s += fabsf(a.z - 2.f * a.w + a4) + fabsf(a.w - 2.f * a4 + a5);
            acc += s;
        }
        // g_yy
        if (hy3)
            acc += fabsf(a.x - 2.f * b.x + c.x) + fabsf(a.y - 2.f * b.y + c.y)
                 + fabsf(a.z - 2.f * b.z + c.z) + fabsf(a.w - 2.f * b.w + c.w);
        // g_zz (weight CONTIZ^2 = 0.5)
        if (dz3)
            acc += W_Z * (fabsf(a.x - 2.f * e.x + f.x) + fabsf(a.y - 2.f * e.y + f.y)
                        + fabsf(a.z - 2.f * e.z + f.z) + fabsf(a.w - 2.f * e.w + f.w));
        // g_xy (weight 2)
        if (hy2) {
            float t = fabsf(a.x - a.y - b.x + b.y) + fabsf(a.y - a.z - b.y + b.z)
                    + fabsf(a.z - a.w - b.z + b.w);
            if (hasW) t += fabsf(a.w - a4 - b.w + b4);
            acc += W_XY * t;
        }
        // g_xz (weight 2*CONTIZ)
        if (dz2) {
            float t = fabsf(a.x - a.y - e.x + e.y) + fabsf(a.y - a.z - e.y + e.z)
                    + fabsf(a.z - a.w - e.z + e.w);
            if (hasW) t += fabsf(a.w - a4 - e.w + e4);
            acc += W_XZ * t;
        }
        // g_yz (weight 2*CONTIZ)
        if (dz2 && hy2)
            acc += W_XZ * (fabsf(a.x - b.x - e.x + g.x) + fabsf(a.y - b.y - e.y + g.y)
                         + fabsf(a.z - b.z - e.z + g.z) + fabsf(a.w - b.w - e.w + g.w));
    }

    // wave (64-lane) shuffle reduce
    for (int off = 32; off > 0; off >>= 1)
        acc += __shfl_down(acc, off, 64);

    __shared__ float ws[TPB / 64];
    const int lane = threadIdx.x & 63;
    const int wv   = threadIdx.x >> 6;
    if (lane == 0) ws[wv] = acc;
    __syncthreads();
    if (threadIdx.x == 0) {
        float bsum = 0.f;
        #pragma unroll
        for (int i = 0; i < TPB / 64; ++i) bsum += ws[i];
        atomicAdd(out, bsum * (1.0f / (IH * IW)));
    }
}

extern "C" void kernel_launch(void* const* d_in, const int* in_sizes, int n_in,
                              void* d_out, int out_size, void* d_ws, size_t ws_size,
                              hipStream_t stream) {
    const float* img = (const float*)d_in[0];
    float* out = (float*)d_out;
    // d_out is re-poisoned to 0xAA before every timed launch -> zero it on-stream.
    hipMemsetAsync(out, 0, sizeof(float), stream);
    hipLaunchKernelGGL(HessianReg_kernel, dim3(BLOCKS), dim3(TPB), 0, stream, img, out);
}

// Round 3
// 197.192 us; speedup vs baseline: 1.1258x; 1.1258x over previous
//
#include <hip/hip_runtime.h>

namespace {
constexpr int IW = 512;
constexpr int IH = 512;
constexpr int ID = 64;
constexpr int PS = IH * IW;                      // plane stride (floats)
constexpr float W_Z  = 0.5f;                     // CONTIZ^2
constexpr float W_XY = 2.0f;
constexpr float W_XZ = 1.41421356237309515f;     // 2*CONTIZ = sqrt(2)

constexpr int TPB    = 256;
constexpr int BLOCKS = 1024;    // 2(n) x 2(seg) x 512(h) x 128(chunk) / TPB
constexpr int DSEG   = ID / 2;  // 32 d-steps per segment
}

__global__ __launch_bounds__(TPB) void HessianReg_kernel(const float* __restrict__ img,
                                                         float* __restrict__ out) {
    // XCD swizzle: physical blocks round-robin XCDs (b%8); remap so each XCD
    // owns 128 consecutive logical blocks = 256 consecutive rows -> y-neighbor
    // rows stay in the same XCD's L2.
    const int lblk = (blockIdx.x & 7) * (BLOCKS / 8) + (blockIdx.x >> 3);
    const int t     = lblk * TPB + threadIdx.x;
    const int chunk = t & 127;          // float4 index within row
    const int r     = t >> 7;
    const int h     = r & (IH - 1);
    const int q     = r >> 9;           // [0,4)
    const int n     = q & 1;
    const int seg   = q >> 1;
    const int d0    = seg * DSEG;
    const int w0    = chunk << 2;

    const bool hasW = (w0 < IW - 4);
    const bool hy2  = (h < IH - 1);
    const bool hy3  = (h < IH - 2);

    const float* p = img + ((size_t)((n * ID + d0) * IH + h)) * IW + w0;

    const float4 Z4 = make_float4(0.f, 0.f, 0.f, 0.f);
    const float2 Z2 = make_float2(0.f, 0.f);

    // Rolling state: A=(d,h) B=(d,h+1) E=(d+1,h); tails a45=A[+4,+5], e45=E[+4,+5], b4=B[+4]
    float4 A = *(const float4*)p;
    float2 a45 = Z2;
    if (hasW) a45 = *(const float2*)(p + 4);
    float4 B = Z4; float b4 = 0.f;
    if (hy2) { B = *(const float4*)(p + IW); if (hasW) b4 = p[IW + 4]; }
    float4 E = *(const float4*)(p + PS);        // d0+1 <= 33 < 64: always valid
    float2 e45 = Z2;
    if (hasW) e45 = *(const float2*)(p + PS + 4);

    float acc = 0.f;

    for (int dl = 0; dl < DSEG; ++dl) {
        const int d = d0 + dl;
        const bool gz2 = (d < ID - 1);  // wave-uniform scalar preds
        const bool gz3 = (d < ID - 2);

        // New loads this step: C=(d,h+2) G=(d+1,h+1) F=(d+2,h) + tails
        float4 C = Z4;
        if (hy3) C = *(const float4*)(p + 2 * IW);
        float4 G = Z4; float g4 = 0.f;
        if (gz2 && hy2) { G = *(const float4*)(p + PS + IW); if (hasW) g4 = p[PS + IW + 4]; }
        float4 F = Z4; float2 f45 = Z2;
        if (gz3) { F = *(const float4*)(p + 2 * PS); if (hasW) f45 = *(const float2*)(p + 2 * PS + 4); }

        // g_xx (weight 1)
        {
            float s = fabsf(A.x - 2.f * A.y + A.z) + fabsf(A.y - 2.f * A.z + A.w);
            if (hasW) s += fabsf(A.z - 2.f * A.w + a45.x) + fabsf(A.w - 2.f * a45.x + a45.y);
            acc += s;
        }
        // g_yy (weight 1)
        if (hy3)
            acc += fabsf(A.x - 2.f * B.x + C.x) + fabsf(A.y - 2.f * B.y + C.y)
                 + fabsf(A.z - 2.f * B.z + C.z) + fabsf(A.w - 2.f * B.w + C.w);
        // g_zz (weight 0.5)
        if (gz3)
            acc += W_Z * (fabsf(A.x - 2.f * E.x + F.x) + fabsf(A.y - 2.f * E.y + F.y)
                        + fabsf(A.z - 2.f * E.z + F.z) + fabsf(A.w - 2.f * E.w + F.w));
        // g_xy (weight 2)
        if (hy2) {
            float s = fabsf(A.x - A.y - B.x + B.y) + fabsf(A.y - A.z - B.y + B.z)
                    + fabsf(A.z - A.w - B.z + B.w);
            if (hasW) s += fabsf(A.w - a45.x - B.w + b4);
            acc += W_XY * s;
        }
        // g_xz (weight sqrt(2))
        if (gz2) {
            float s = fabsf(A.x - A.y - E.x + E.y) + fabsf(A.y - A.z - E.y + E.z)
                    + fabsf(A.z - A.w - E.z + E.w);
            if (hasW) s += fabsf(A.w - a45.x - E.w + e45.x);
            acc += W_XZ * s;
        }
        // g_yz (weight sqrt(2))
        if (gz2 && hy2)
            acc += W_XZ * (fabsf(A.x - B.x - E.x + G.x) + fabsf(A.y - B.y - E.y + G.y)
                         + fabsf(A.z - B.z - E.z + G.z) + fabsf(A.w - B.w - E.w + G.w));

        // roll z
        A = E; a45 = e45;
        B = G; b4 = g4;
        E = F; e45 = f45;
        p += PS;
    }

    // wave (64-lane) shuffle reduce
    for (int off = 32; off > 0; off >>= 1)
        acc += __shfl_down(acc, off, 64);

    __shared__ float ws[TPB / 64];
    const int lane = threadIdx.x & 63;
    const int wv   = threadIdx.x >> 6;
    if (lane == 0) ws[wv] = acc;
    __syncthreads();
    if (threadIdx.x == 0) {
        float bsum = 0.f;
        #pragma unroll
        for (int i = 0; i < TPB / 64; ++i) bsum += ws[i];
        atomicAdd(out, bsum * (1.0f / (IH * IW)));
    }
}

extern "C" void kernel_launch(void* const* d_in, const int* in_sizes, int n_in,
                              void* d_out, int out_size, void* d_ws, size_t ws_size,
                              hipStream_t stream) {
    const float* img = (const float*)d_in[0];
    float* out = (float*)d_out;
    // d_out is re-poisoned to 0xAA before every timed launch -> zero it on-stream.
    hipMemsetAsync(out, 0, sizeof(float), stream);
    hipLaunchKernelGGL(HessianReg_kernel, dim3(BLOCKS), dim3(TPB), 0, stream, img, out);
}